// Round 6
// baseline (614.167 us; speedup 1.0000x reference)
//
#include <hip/hip_runtime.h>

typedef unsigned short u16;
typedef __attribute__((ext_vector_type(8))) short short8;
typedef __attribute__((ext_vector_type(8))) unsigned short ushort8;
typedef __attribute__((ext_vector_type(4))) unsigned short ushort4v;
typedef __attribute__((ext_vector_type(4))) float f32x4;

#define NB 4
#define SS 4096
#define DD 1024
#define CFENCE asm volatile("" ::: "memory")

__device__ __forceinline__ u16 f2bf(float x) {
  unsigned u = __builtin_bit_cast(unsigned, x);
  u = (u + 0x7FFFu + ((u >> 16) & 1u)) >> 16;
  return (u16)u;
}
__device__ __forceinline__ float bf2f(u16 b) {
  unsigned u = ((unsigned)b) << 16;
  return __builtin_bit_cast(float, u);
}
__device__ __forceinline__ void gload16(const void* g, void* l) {
  __builtin_amdgcn_global_load_lds((const __attribute__((address_space(1))) void*)g,
                                   (__attribute__((address_space(3))) void*)l, 16, 0, 0);
}
// bijective XCD-aware swizzle (m204)
__device__ __forceinline__ int xcd_swz(int bid, int nwg) {
  const int x = bid & 7, idx = bid >> 3;
  const int q = nwg >> 3, r = nwg & 7;
  return (x < r ? x * (q + 1) : r * (q + 1) + (x - r) * q) + idx;
}

// ---------------- kernel 1: logits (f32), loss partials, pred, h->bf16 -----
__global__ __launch_bounds__(256) void k_logits(
    const float* __restrict__ h, const int* __restrict__ lab,
    const float* __restrict__ Wl, const float* __restrict__ bl,
    u16* __restrict__ h16, int* __restrict__ pred, float* __restrict__ lossPart)
{
  const int t = threadIdx.x, w = t >> 6, lane = t & 63;
  const int tok = blockIdx.x * 4 + w;
  const float4* h4p = (const float4*)(h + (size_t)tok * DD);
  const float4* wl4 = (const float4*)Wl;
  float p0 = 0.f, p1 = 0.f, p2 = 0.f, p3 = 0.f;
#pragma unroll
  for (int i = 0; i < 4; ++i) {
    const int d = i * 256 + lane * 4;
    float4 hv = h4p[i * 64 + lane];
    ushort4v hb;
    hb[0] = f2bf(hv.x); hb[1] = f2bf(hv.y); hb[2] = f2bf(hv.z); hb[3] = f2bf(hv.w);
    *(ushort4v*)(h16 + (size_t)tok * DD + d) = hb;
    float4 w0 = wl4[d], w1 = wl4[d + 1], w2 = wl4[d + 2], w3 = wl4[d + 3];
    p0 += hv.x * w0.x + hv.y * w1.x + hv.z * w2.x + hv.w * w3.x;
    p1 += hv.x * w0.y + hv.y * w1.y + hv.z * w2.y + hv.w * w3.y;
    p2 += hv.x * w0.z + hv.y * w1.z + hv.z * w2.z + hv.w * w3.z;
    p3 += hv.x * w0.w + hv.y * w1.w + hv.z * w2.w + hv.w * w3.w;
  }
#pragma unroll
  for (int m = 32; m; m >>= 1) {
    p0 += __shfl_xor(p0, m); p1 += __shfl_xor(p1, m);
    p2 += __shfl_xor(p2, m); p3 += __shfl_xor(p3, m);
  }
  __shared__ float ls[4];
  if (lane == 0) {
    float l[4] = {p0 + bl[0], p1 + bl[1], p2 + bl[2], p3 + bl[3]};
    int bi = 0; float bv = l[0];
#pragma unroll
    for (int c = 1; c < 4; ++c) if (l[c] > bv) { bv = l[c]; bi = c; }
    pred[tok] = bi;
    float se = 0.f;
#pragma unroll
    for (int c = 0; c < 4; ++c) se += expf(l[c] - bv);
    float lse = bv + logf(se);
    ls[w] = lse - l[lab[tok]];
  }
  __syncthreads();
  if (t == 0) lossPart[blockIdx.x] = ls[0] + ls[1] + ls[2] + ls[3];
}

// ---------------- kernel 2: weights -> transposed bf16 ---------------------
__global__ __launch_bounds__(256) void k_wconv(
    const float* __restrict__ W0, const float* __restrict__ W1,
    const float* __restrict__ W2, const float* __restrict__ W3,
    u16* __restrict__ Wt)
{
  const int gid = blockIdx.x * 256 + threadIdx.x;
  const int mat = gid >> 20;
  const int rem = gid & ((1 << 20) - 1);
  const int n = rem >> 10, k = rem & 1023;
  const float* W = (mat == 0) ? W0 : (mat == 1) ? W1 : (mat == 2) ? W2 : W3;
  Wt[((size_t)mat << 20) + (size_t)n * 1024 + k] = f2bf(W[(size_t)k * 1024 + n]);
}

// ---------------- kernel 3: BIOS chunk scan (1 block / batch) --------------
__global__ __launch_bounds__(256) void k_scan(
    const int* __restrict__ pred, int* __restrict__ cstart, int* __restrict__ ccnt)
{
  const int b = blockIdx.x, t = threadIdx.x;
  const int4* p4 = (const int4*)(pred + (size_t)b * SS);
  int labv[16];
#pragma unroll
  for (int i = 0; i < 4; ++i) {
    int4 v = p4[t * 4 + i];
    labv[i * 4 + 0] = v.x; labv[i * 4 + 1] = v.y;
    labv[i * 4 + 2] = v.z; labv[i * 4 + 3] = v.w;
  }
  int A = 0, Bc = 1;
#pragma unroll
  for (int e = 0; e < 16; ++e) {
    int a = (labv[e] == 0), bb = (labv[e] == 1);
    A = a | (bb & A);
    Bc = bb & Bc;
  }
  __shared__ int sA[256], sB[256], sC[256];
  sA[t] = A; sB[t] = Bc;
  __syncthreads();
  for (int off = 1; off < 256; off <<= 1) {
    int pa = 0, pb = 1;
    if (t >= off) { pa = sA[t - off]; pb = sB[t - off]; }
    __syncthreads();
    A = A | (Bc & pa); Bc = Bc & pb;
    sA[t] = A; sB[t] = Bc;
    __syncthreads();
  }
  const int extIn = (t == 0) ? 0 : sA[t - 1];
  int ext = extIn, nst = 0;
#pragma unroll
  for (int e = 0; e < 16; ++e) {
    int cont = (labv[e] == 1) & ext;
    nst += !cont;
    ext = (labv[e] == 0) | cont;
  }
  sC[t] = nst;
  __syncthreads();
  int tot = nst;
  for (int off = 1; off < 256; off <<= 1) {
    int pc = 0;
    if (t >= off) pc = sC[t - off];
    __syncthreads();
    tot += pc;
    sC[t] = tot;
    __syncthreads();
  }
  const int base = tot - nst;
  const int total = sC[255];
  if (t == 0) { ccnt[b] = total; cstart[b * (SS + 1) + total] = SS; }
  ext = extIn; int id = base;
#pragma unroll
  for (int e = 0; e < 16; ++e) {
    int cont = (labv[e] == 1) & ext;
    if (!cont) cstart[b * (SS + 1) + id++] = t * 16 + e;
    ext = (labv[e] == 0) | cont;
  }
}

// ---------------- kernel 4: segment-mean pooling (1 wave / chunk) ----------
__global__ __launch_bounds__(256) void k_pool(
    const float* __restrict__ h, const int* __restrict__ cstart,
    const int* __restrict__ ccnt, u16* __restrict__ cemb)
{
  const int t = threadIdx.x, w = t >> 6, lane = t & 63;
  const int gw = blockIdx.x * 4 + w;
  const int b = gw >> 12, c = gw & (SS - 1);
  u16* out = cemb + (size_t)gw * DD + lane * 16;
  if (c >= ccnt[b]) {
    ushort8 z = {0, 0, 0, 0, 0, 0, 0, 0};
    *(ushort8*)out = z; *(ushort8*)(out + 8) = z;
    return;
  }
  const int s0 = cstart[b * (SS + 1) + c], s1 = cstart[b * (SS + 1) + c + 1];
  float acc[16] = {};
  for (int s = s0; s < s1; ++s) {
    const float4* hp = (const float4*)(h + ((size_t)b * SS + s) * DD + lane * 16);
#pragma unroll
    for (int ii = 0; ii < 4; ++ii) {
      float4 v = hp[ii];
      acc[ii * 4 + 0] += v.x; acc[ii * 4 + 1] += v.y;
      acc[ii * 4 + 2] += v.z; acc[ii * 4 + 3] += v.w;
    }
  }
  const float inv = 1.f / (float)(s1 - s0);
  ushort8 o0, o1;
#pragma unroll
  for (int e = 0; e < 8; ++e) { o0[e] = f2bf(acc[e] * inv); o1[e] = f2bf(acc[8 + e] * inv); }
  *(ushort8*)out = o0; *(ushort8*)(out + 8) = o1;
}

// ---------------- 256x256 NT bf16 GEMM, BK=64, 8 waves ----------------------
// 4 phases/K-tile, ONE barrier per phase, reads one phase ahead so LDS latency
// drains under MFMA (counted lgkmcnt). Fixed register roles:
//   afA=A-mh0(j), afB=A-mh1(j), bA=B-nh0(j), bB=B-nh1(j).
// Quadrant order (gray): P0=(0,0) P1=(0,1) P2=(1,1) P3=(1,0).
// Reads:   P3bottom: afA,bA(j+1) [12]   P0top: bB(j) [4]   P1top: afB(j) [8]
// Waits:   P0: lgkm(4) [afA,bA done]    P1: lgkm(8) [bB]   P2: lgkm(0) [afB]
// Stages (tile j+2 -> buf[j&1]):  P1: SA0+SB0 (4)  P2: SB1 (2)  P3: SA1 (2)
//   WAR: each overwritten region's reads all-waves-confirmed one barrier prior.
// vmcnt gate at P2 (before its barrier): vmcnt(6) confirms tile j+1 fully
// staged (vmcnt(0) at j==NT-2) => P3-bottom reads of buf[j+1] cross-wave safe.
template <int OUTF32>
__global__ __launch_bounds__(512, 2) void gemm256(
    const u16* __restrict__ A0p, const u16* __restrict__ A1p,
    const u16* __restrict__ A2p, const u16* __restrict__ A3p,
    const u16* __restrict__ Bt, long strideB,
    void* __restrict__ C0, void* __restrict__ C1,
    void* __restrict__ C2, void* __restrict__ C3,
    const float* __restrict__ bias, float scale, int M, int N, int K)
{
  __shared__ u16 lds[65536];  // 128 KB: A dbuf | B dbuf; C-tile overlay after
  u16* ldsA = lds;
  u16* ldsB = lds + 32768;
  const int t = threadIdx.x, lane = t & 63, w = t >> 6;
  const int wr = w >> 2, wc = w & 3;
  const int z = blockIdx.z;
  const u16* A = (z == 0) ? A0p : (z == 1) ? A1p : (z == 2) ? A2p : A3p;
  void* Cp    = (z == 0) ? C0 : (z == 1) ? C1 : (z == 2) ? C2 : C3;
  const u16* B = Bt + (size_t)z * strideB;
  const int bid = blockIdx.y * gridDim.x + blockIdx.x;
  const int swz = xcd_swz(bid, gridDim.x * gridDim.y);
  const int m0 = (swz / gridDim.x) * 256, n0 = (swz % gridDim.x) * 256;

  f32x4 acc[8][4];
#pragma unroll
  for (int i = 0; i < 8; ++i)
#pragma unroll
    for (int j = 0; j < 4; ++j) acc[i][j] = (f32x4){0.f, 0.f, 0.f, 0.f};

  const int trow = t >> 3;
  const u16* Ag = A + (size_t)(m0 + trow) * K + ((t & 7) ^ (trow & 7)) * 8;
  const u16* Bg = B + (size_t)(n0 + trow) * K + ((t & 7) ^ (trow & 7)) * 8;
  u16* dA = ldsA + t * 8;
  u16* dB = ldsB + t * 8;

#define STG_A0(BUF, KT) { gload16(Ag + (size_t)(KT),            dA + (BUF) * 16384 + 0 * 4096); \
                          gload16(Ag + (size_t)128 * K + (KT),  dA + (BUF) * 16384 + 2 * 4096); }
#define STG_A1(BUF, KT) { gload16(Ag + (size_t)64 * K + (KT),   dA + (BUF) * 16384 + 1 * 4096); \
                          gload16(Ag + (size_t)192 * K + (KT),  dA + (BUF) * 16384 + 3 * 4096); }
#define STG_B0(BUF, KT) { gload16(Bg + (size_t)(KT),            dB + (BUF) * 16384 + 0 * 4096); \
                          gload16(Bg + (size_t)64 * K + (KT),   dB + (BUF) * 16384 + 1 * 4096); }
#define STG_B1(BUF, KT) { gload16(Bg + (size_t)128 * K + (KT),  dB + (BUF) * 16384 + 2 * 4096); \
                          gload16(Bg + (size_t)192 * K + (KT),  dB + (BUF) * 16384 + 3 * 4096); }
#define RD_A(DST, BASE, ROFF) \
  { _Pragma("unroll") for (int mi = 0; mi < 4; ++mi) { \
      DST[mi][0] = *(const short8*)((BASE) + (wr * 128 + (ROFF) + mi * 16 + lrow) * 64 + co0); \
      DST[mi][1] = *(const short8*)((BASE) + (wr * 128 + (ROFF) + mi * 16 + lrow) * 64 + co1); } }
#define RD_B(DST, BASE, ROFF) \
  { _Pragma("unroll") for (int ni = 0; ni < 2; ++ni) { \
      DST[ni][0] = *(const short8*)((BASE) + ((ROFF) + wc * 32 + ni * 16 + lrow) * 64 + co0); \
      DST[ni][1] = *(const short8*)((BASE) + ((ROFF) + wc * 32 + ni * 16 + lrow) * 64 + co1); } }
#define MFMA16(MH, AF, BF, NOFF) \
  { _Pragma("unroll") for (int ks = 0; ks < 2; ++ks) \
    _Pragma("unroll") for (int mi = 0; mi < 4; ++mi) \
      _Pragma("unroll") for (int ni = 0; ni < 2; ++ni) \
        acc[(MH) * 4 + mi][(NOFF) + ni] = __builtin_amdgcn_mfma_f32_16x16x32_bf16( \
            AF[mi][ks], BF[ni][ks], acc[(MH) * 4 + mi][(NOFF) + ni], 0, 0, 0); }

  const int lrow = lane & 15, hi = lane >> 4;
  const int co0 = (hi ^ (lrow & 7)) * 8;
  const int co1 = ((4 + hi) ^ (lrow & 7)) * 8;

  const int NT = K >> 6;
  // prologue: tile0 + tile1 fully staged (16 loads); confirm tile0; read q0(0)
  STG_A0(0, 0); STG_B0(0, 0); STG_B1(0, 0); STG_A1(0, 0);
  if (NT > 1) {
    STG_A0(1, 64); STG_B0(1, 64); STG_B1(1, 64); STG_A1(1, 64);
    asm volatile("s_waitcnt vmcnt(8)" ::: "memory");
  } else {
    asm volatile("s_waitcnt vmcnt(0)" ::: "memory");
  }
  __builtin_amdgcn_s_barrier();
  CFENCE;
  short8 afA[4][2], afB[4][2], bA[2][2], bB[2][2];
  RD_A(afA, ldsA, 0);
  RD_B(bA, ldsB, 0);
  CFENCE;

  for (int j = 0; j < NT; ++j) {
    const int cur = j & 1;
    const u16* bufA = ldsA + cur * 16384;
    const u16* bufB = ldsB + cur * 16384;
    const u16* nbufA = ldsA + (cur ^ 1) * 16384;
    const u16* nbufB = ldsB + (cur ^ 1) * 16384;
    const int kt2 = (j + 2) << 6;
    // ---- P0: read bB(j); wait afA,bA; MFMA (0,0)
    RD_B(bB, bufB, 128);
    CFENCE;
    asm volatile("s_waitcnt lgkmcnt(4)" ::: "memory");
    __builtin_amdgcn_sched_barrier(0);
    __builtin_amdgcn_s_setprio(1);
    MFMA16(0, afA, bA, 0);
    __builtin_amdgcn_s_setprio(0);
    __builtin_amdgcn_sched_barrier(0);
    __builtin_amdgcn_s_barrier();
    CFENCE;
    // ---- P1: read afB(j); stage SA0,SB0(j+2); wait bB; MFMA (0,1)
    RD_A(afB, bufA, 64);
    if (j + 2 < NT) { STG_A0(cur, kt2); STG_B0(cur, kt2); }
    CFENCE;
    asm volatile("s_waitcnt lgkmcnt(8)" ::: "memory");
    __builtin_amdgcn_sched_barrier(0);
    __builtin_amdgcn_s_setprio(1);
    MFMA16(0, afA, bB, 2);
    __builtin_amdgcn_s_setprio(0);
    __builtin_amdgcn_sched_barrier(0);
    __builtin_amdgcn_s_barrier();
    CFENCE;
    // ---- P2: stage SB1(j+2); wait afB; MFMA (1,1); vmcnt gate for tile j+1
    if (j + 2 < NT) STG_B1(cur, kt2);
    CFENCE;
    asm volatile("s_waitcnt lgkmcnt(0)" ::: "memory");
    __builtin_amdgcn_sched_barrier(0);
    __builtin_amdgcn_s_setprio(1);
    MFMA16(1, afB, bB, 2);
    __builtin_amdgcn_s_setprio(0);
    if (j + 1 < NT) {
      if (j + 2 < NT) asm volatile("s_waitcnt vmcnt(6)" ::: "memory");
      else            asm volatile("s_waitcnt vmcnt(0)" ::: "memory");
    }
    __builtin_amdgcn_sched_barrier(0);
    __builtin_amdgcn_s_barrier();
    CFENCE;
    // ---- P3: stage SA1(j+2); MFMA (1,0); read afA,bA(j+1) under next barrier
    if (j + 2 < NT) STG_A1(cur, kt2);
    CFENCE;
    __builtin_amdgcn_sched_barrier(0);
    __builtin_amdgcn_s_setprio(1);
    MFMA16(1, afB, bA, 0);
    __builtin_amdgcn_s_setprio(0);
    __builtin_amdgcn_sched_barrier(0);
    if (j + 1 < NT) {
      RD_A(afA, nbufA, 0);
      RD_B(bA, nbufB, 0);
    }
    CFENCE;
    __builtin_amdgcn_s_barrier();
    CFENCE;
  }

  // epilogue. frag (m,n): row_local = wr*128 + m*16 + (lane>>4)*4 + q,
  // col_local = (n>>1)*128 + wc*32 + (n&1)*16 + (lane&15)
  if (OUTF32) {
    const int rowb = m0 + wr * 128 + (lane >> 4) * 4;
#pragma unroll
    for (int n = 0; n < 4; ++n) {
      const int col = n0 + (n >> 1) * 128 + wc * 32 + (n & 1) * 16 + (lane & 15);
      const float bv = bias ? bias[col] : 0.f;
#pragma unroll
      for (int m = 0; m < 8; ++m)
#pragma unroll
        for (int q = 0; q < 4; ++q)
          ((float*)Cp)[(size_t)(rowb + m * 16 + q) * N + col] = acc[m][n][q] * scale + bv;
    }
  } else {
    // stage C tile in LDS with row-XOR col swizzle (kills 4-way ds_write conflict)
    __syncthreads();
    u16* cls = lds;
    const int rowl = wr * 128 + (lane >> 4) * 4;
#pragma unroll
    for (int n = 0; n < 4; ++n) {
      const int coll = (n >> 1) * 128 + wc * 32 + (n & 1) * 16 + (lane & 15);
      const float bv = bias ? bias[n0 + coll] : 0.f;
#pragma unroll
      for (int m = 0; m < 8; ++m)
#pragma unroll
        for (int q = 0; q < 4; ++q) {
          const int row = rowl + m * 16 + q;
          cls[row * 256 + (coll ^ (((row >> 2) & 3) << 4))] = f2bf(acc[m][n][q] * scale + bv);
        }
    }
    __syncthreads();
    u16* Cu = (u16*)Cp;
#pragma unroll
    for (int ps = 0; ps < 16; ++ps) {
      const int f = ps * 512 + t;
      const int row = f >> 5, col8 = (f & 31);
      const int scol8 = col8 ^ (((row >> 2) & 3) << 1);
      *(ushort8*)(Cu + (size_t)(m0 + row) * N + n0 + col8 * 8) =
          *(const ushort8*)(cls + row * 256 + scol8 * 8);
    }
  }
#undef STG_A0
#undef STG_A1
#undef STG_B0
#undef STG_B1
#undef RD_A
#undef RD_B
#undef MFMA16
}

// ---------------- masked row softmax, bf16 in-place, z-folded ---------------
__global__ __launch_bounds__(256) void k_softmax(
    u16* __restrict__ s0, u16* __restrict__ s1,
    u16* __restrict__ s2, u16* __restrict__ s3, const int* __restrict__ ccnt)
{
  const int t = threadIdx.x, lane = t & 63, w = t >> 6;
  const int row = blockIdx.x, b = blockIdx.y;
  u16* sc = (b == 0) ? s0 : (b == 1) ? s1 : (b == 2) ? s2 : s3;
  const int Cb = ccnt[b];
  u16* p = sc + (size_t)row * SS + t * 16;
  ushort8 v0 = *(ushort8*)p, v1 = *(ushort8*)(p + 8);
  float x[16];
#pragma unroll
  for (int e = 0; e < 8; ++e) { x[e] = bf2f(v0[e]); x[8 + e] = bf2f(v1[e]); }
  const int cb0 = t * 16;
  float m = -1e30f;
#pragma unroll
  for (int e = 0; e < 16; ++e) if (cb0 + e < Cb) m = fmaxf(m, x[e]);
#pragma unroll
  for (int off = 32; off; off >>= 1) m = fmaxf(m, __shfl_xor(m, off));
  __shared__ float red[4], red2[4];
  if (lane == 0) red[w] = m;
  __syncthreads();
  m = fmaxf(fmaxf(red[0], red[1]), fmaxf(red[2], red[3]));
  float ssum = 0.f;
#pragma unroll
  for (int e = 0; e < 16; ++e) {
    float ev = (cb0 + e < Cb) ? __expf(x[e] - m) : 0.f;
    x[e] = ev; ssum += ev;
  }
#pragma unroll
  for (int off = 32; off; off >>= 1) ssum += __shfl_xor(ssum, off);
  if (lane == 0) red2[w] = ssum;
  __syncthreads();
  ssum = red2[0] + red2[1] + red2[2] + red2[3];
  const float inv = 1.f / ssum;
#pragma unroll
  for (int e = 0; e < 8; ++e) { v0[e] = f2bf(x[e] * inv); v1[e] = f2bf(x[8 + e] * inv); }
  *(ushort8*)p = v0; *(ushort8*)(p + 8) = v1;
}

// ---------------- bf16 transpose v[b][c][d] -> vT[b][d][c] ------------------
__global__ __launch_bounds__(256) void k_transpose(
    const u16* __restrict__ v, u16* __restrict__ vt)
{
  __shared__ u16 ts[64][80];
  const int t = threadIdx.x;
  const int d0 = blockIdx.x * 64, c0 = blockIdx.y * 64, b = blockIdx.z;
#pragma unroll
  for (int p = 0; p < 2; ++p) {
    const int idx = p * 256 + t, r = idx >> 3, cc = idx & 7;
    ushort8 val = *(const ushort8*)(v + ((size_t)b * SS + c0 + r) * DD + d0 + cc * 8);
    *(ushort8*)&ts[r][cc * 8] = val;
  }
  __syncthreads();
#pragma unroll
  for (int p = 0; p < 2; ++p) {
    const int idx = p * 256 + t, r = idx >> 3, cc = idx & 7;
    ushort8 o;
#pragma unroll
    for (int e = 0; e < 8; ++e) o[e] = ts[cc * 8 + e][r];
    *(ushort8*)(vt + ((size_t)b * DD + d0 + r) * SS + c0 + cc * 8) = o;
  }
}

// ---------------- loss finalize ---------------------------------------------
__global__ __launch_bounds__(256) void k_lossfin(
    const float* __restrict__ part, float* __restrict__ out)
{
  const int t = threadIdx.x, lane = t & 63, w = t >> 6;
  float s = 0.f;
  for (int i = t; i < 4096; i += 256) s += part[i];
#pragma unroll
  for (int off = 32; off; off >>= 1) s += __shfl_xor(s, off);
  __shared__ float r[4];
  if (lane == 0) r[w] = s;
  __syncthreads();
  if (t == 0) out[0] = (r[0] + r[1] + r[2] + r[3]) * (1.f / (NB * SS));
}

extern "C" void kernel_launch(void* const* d_in, const int* in_sizes, int n_in,
                              void* d_out, int out_size, void* d_ws, size_t ws_size,
                              hipStream_t stream) {
  const float* h  = (const float*)d_in[0];
  const int* plab = (const int*)d_in[1];
  const float* Wl = (const float*)d_in[2];
  const float* bl = (const float*)d_in[3];
  const float* Wq = (const float*)d_in[4];
  const float* bq = (const float*)d_in[5];
  const float* Wk = (const float*)d_in[6];
  const float* bk = (const float*)d_in[7];
  const float* Wv = (const float*)d_in[8];
  const float* bv = (const float*)d_in[9];
  const float* Wo = (const float*)d_in[10];
  const float* bo = (const float*)d_in[11];
  float* out = (float*)d_out;

  char* ws = (char*)d_ws;
  const size_t SZ = (size_t)NB * SS * DD * 2;  // 32 MB
  const size_t SD = (size_t)SS * DD;           // per-batch elems
  u16* h16      = (u16*)(ws + 0 * SZ);  // dead after q GEMM -> scores[2]
  u16* cemb     = (u16*)(ws + 1 * SZ);  // dead after k,v GEMM -> scores[3]
  u16* q        = (u16*)(ws + 2 * SZ);
  u16* kk       = (u16*)(ws + 3 * SZ);
  u16* vv       = (u16*)(ws + 4 * SZ);  // dead after transpose -> attended
  u16* vt       = (u16*)(ws + 5 * SZ);
  u16* Wt       = (u16*)(ws + 6 * SZ);  // 8 MB
  char* ws2     = ws + 6 * SZ + (size_t)4 * 1024 * 1024 * 2;
  int* pred     = (int*)ws2;
  int* cstart   = (int*)(ws2 + 65536);
  int* ccnt     = (int*)(ws2 + 65536 + 4 * (SS + 1) * 4);
  float* lossPart = (float*)(ws2 + 65536 + 4 * (SS + 1) * 4 + 64);
  u16* s0 = (u16*)d_out;                       // scores borrow d_out + dead bufs
  u16* s1 = (u16*)d_out + (size_t)SS * SS;
  u16* s2 = h16;
  u16* s3 = cemb;
  u16* att = vv;

  k_logits<<<dim3(NB * SS / 4), 256, 0, stream>>>(h, plab, Wl, bl, h16, pred, lossPart);
  k_wconv<<<dim3(4 * 1024 * 1024 / 256), 256, 0, stream>>>(Wq, Wk, Wv, Wo, Wt);
  k_scan<<<dim3(NB), 256, 0, stream>>>(pred, cstart, ccnt);
  k_pool<<<dim3(NB * SS / 4), 256, 0, stream>>>(h, cstart, ccnt, cemb);

  gemm256<0><<<dim3(DD / 256, NB * SS / 256, 1), 512, 0, stream>>>(
      h16, h16, h16, h16, Wt, 0, q, q, q, q, bq, 1.f, NB * SS, DD, DD);
  gemm256<0><<<dim3(DD / 256, NB * SS / 256, 1), 512, 0, stream>>>(
      cemb, cemb, cemb, cemb, Wt + (1 << 20), 0, kk, kk, kk, kk, bk, 1.f, NB * SS, DD, DD);
  gemm256<0><<<dim3(DD / 256, NB * SS / 256, 1), 512, 0, stream>>>(
      cemb, cemb, cemb, cemb, Wt + 2 * (1 << 20), 0, vv, vv, vv, vv, bv, 1.f, NB * SS, DD, DD);
  k_transpose<<<dim3(DD / 64, SS / 64, NB), 256, 0, stream>>>(vv, vt);

  const float scl = 1.f / 32.f;  // 1/sqrt(DC)
  gemm256<0><<<dim3(SS / 256, SS / 256, NB), 512, 0, stream>>>(
      q, q + SD, q + 2 * SD, q + 3 * SD, kk, (long)SD,
      s0, s1, s2, s3, nullptr, scl, SS, SS, DD);
  k_softmax<<<dim3(SS, NB), 256, 0, stream>>>(s0, s1, s2, s3, ccnt);
  gemm256<0><<<dim3(DD / 256, SS / 256, NB), 512, 0, stream>>>(
      s0, s1, s2, s3, vt, (long)SD,
      att, att + SD, att + 2 * SD, att + 3 * SD, nullptr, 1.f, SS, DD, SS);
  gemm256<1><<<dim3(DD / 256, NB * SS / 256, 1), 512, 0, stream>>>(
      att, att, att, att, Wt + 3 * (1 << 20), 0, out, out, out, out, bo, 1.f, NB * SS, DD, DD);
  k_lossfin<<<dim3(1), 256, 0, stream>>>(lossPart, out + (size_t)NB * SS * DD);
}

// Round 7
// 550.890 us; speedup vs baseline: 1.1149x; 1.1149x over previous
//
#include <hip/hip_runtime.h>

typedef unsigned short u16;
typedef __attribute__((ext_vector_type(8))) short short8;
typedef __attribute__((ext_vector_type(8))) unsigned short ushort8;
typedef __attribute__((ext_vector_type(4))) unsigned short ushort4v;
typedef __attribute__((ext_vector_type(4))) float f32x4;

#define NB 4
#define SS 4096
#define DD 1024
#define CFENCE asm volatile("" ::: "memory")

__device__ __forceinline__ u16 f2bf(float x) {
  unsigned u = __builtin_bit_cast(unsigned, x);
  u = (u + 0x7FFFu + ((u >> 16) & 1u)) >> 16;
  return (u16)u;
}
__device__ __forceinline__ float bf2f(u16 b) {
  unsigned u = ((unsigned)b) << 16;
  return __builtin_bit_cast(float, u);
}
__device__ __forceinline__ void gload16(const void* g, void* l) {
  __builtin_amdgcn_global_load_lds((const __attribute__((address_space(1))) void*)g,
                                   (__attribute__((address_space(3))) void*)l, 16, 0, 0);
}
// bijective XCD-aware swizzle (m204)
__device__ __forceinline__ int xcd_swz(int bid, int nwg) {
  const int x = bid & 7, idx = bid >> 3;
  const int q = nwg >> 3, r = nwg & 7;
  return (x < r ? x * (q + 1) : r * (q + 1) + (x - r) * q) + idx;
}

// ---------------- kernel 1: logits (f32), loss partials, pred, h->bf16 -----
__global__ __launch_bounds__(256) void k_logits(
    const float* __restrict__ h, const int* __restrict__ lab,
    const float* __restrict__ Wl, const float* __restrict__ bl,
    u16* __restrict__ h16, int* __restrict__ pred, float* __restrict__ lossPart)
{
  const int t = threadIdx.x, w = t >> 6, lane = t & 63;
  const int tok = blockIdx.x * 4 + w;
  const float4* h4p = (const float4*)(h + (size_t)tok * DD);
  const float4* wl4 = (const float4*)Wl;
  float p0 = 0.f, p1 = 0.f, p2 = 0.f, p3 = 0.f;
#pragma unroll
  for (int i = 0; i < 4; ++i) {
    const int d = i * 256 + lane * 4;
    float4 hv = h4p[i * 64 + lane];
    ushort4v hb;
    hb[0] = f2bf(hv.x); hb[1] = f2bf(hv.y); hb[2] = f2bf(hv.z); hb[3] = f2bf(hv.w);
    *(ushort4v*)(h16 + (size_t)tok * DD + d) = hb;
    float4 w0 = wl4[d], w1 = wl4[d + 1], w2 = wl4[d + 2], w3 = wl4[d + 3];
    p0 += hv.x * w0.x + hv.y * w1.x + hv.z * w2.x + hv.w * w3.x;
    p1 += hv.x * w0.y + hv.y * w1.y + hv.z * w2.y + hv.w * w3.y;
    p2 += hv.x * w0.z + hv.y * w1.z + hv.z * w2.z + hv.w * w3.z;
    p3 += hv.x * w0.w + hv.y * w1.w + hv.z * w2.w + hv.w * w3.w;
  }
#pragma unroll
  for (int m = 32; m; m >>= 1) {
    p0 += __shfl_xor(p0, m); p1 += __shfl_xor(p1, m);
    p2 += __shfl_xor(p2, m); p3 += __shfl_xor(p3, m);
  }
  __shared__ float ls[4];
  if (lane == 0) {
    float l[4] = {p0 + bl[0], p1 + bl[1], p2 + bl[2], p3 + bl[3]};
    int bi = 0; float bv = l[0];
#pragma unroll
    for (int c = 1; c < 4; ++c) if (l[c] > bv) { bv = l[c]; bi = c; }
    pred[tok] = bi;
    float se = 0.f;
#pragma unroll
    for (int c = 0; c < 4; ++c) se += expf(l[c] - bv);
    float lse = bv + logf(se);
    ls[w] = lse - l[lab[tok]];
  }
  __syncthreads();
  if (t == 0) lossPart[blockIdx.x] = ls[0] + ls[1] + ls[2] + ls[3];
}

// ---------------- kernel 2: weights -> transposed bf16 ---------------------
__global__ __launch_bounds__(256) void k_wconv(
    const float* __restrict__ W0, const float* __restrict__ W1,
    const float* __restrict__ W2, const float* __restrict__ W3,
    u16* __restrict__ Wt)
{
  const int gid = blockIdx.x * 256 + threadIdx.x;
  const int mat = gid >> 20;
  const int rem = gid & ((1 << 20) - 1);
  const int n = rem >> 10, k = rem & 1023;
  const float* W = (mat == 0) ? W0 : (mat == 1) ? W1 : (mat == 2) ? W2 : W3;
  Wt[((size_t)mat << 20) + (size_t)n * 1024 + k] = f2bf(W[(size_t)k * 1024 + n]);
}

// ---------------- kernel 3: BIOS chunk scan (1 block / batch) --------------
__global__ __launch_bounds__(256) void k_scan(
    const int* __restrict__ pred, int* __restrict__ cstart, int* __restrict__ ccnt)
{
  const int b = blockIdx.x, t = threadIdx.x;
  const int4* p4 = (const int4*)(pred + (size_t)b * SS);
  int labv[16];
#pragma unroll
  for (int i = 0; i < 4; ++i) {
    int4 v = p4[t * 4 + i];
    labv[i * 4 + 0] = v.x; labv[i * 4 + 1] = v.y;
    labv[i * 4 + 2] = v.z; labv[i * 4 + 3] = v.w;
  }
  int A = 0, Bc = 1;
#pragma unroll
  for (int e = 0; e < 16; ++e) {
    int a = (labv[e] == 0), bb = (labv[e] == 1);
    A = a | (bb & A);
    Bc = bb & Bc;
  }
  __shared__ int sA[256], sB[256], sC[256];
  sA[t] = A; sB[t] = Bc;
  __syncthreads();
  for (int off = 1; off < 256; off <<= 1) {
    int pa = 0, pb = 1;
    if (t >= off) { pa = sA[t - off]; pb = sB[t - off]; }
    __syncthreads();
    A = A | (Bc & pa); Bc = Bc & pb;
    sA[t] = A; sB[t] = Bc;
    __syncthreads();
  }
  const int extIn = (t == 0) ? 0 : sA[t - 1];
  int ext = extIn, nst = 0;
#pragma unroll
  for (int e = 0; e < 16; ++e) {
    int cont = (labv[e] == 1) & ext;
    nst += !cont;
    ext = (labv[e] == 0) | cont;
  }
  sC[t] = nst;
  __syncthreads();
  int tot = nst;
  for (int off = 1; off < 256; off <<= 1) {
    int pc = 0;
    if (t >= off) pc = sC[t - off];
    __syncthreads();
    tot += pc;
    sC[t] = tot;
    __syncthreads();
  }
  const int base = tot - nst;
  const int total = sC[255];
  if (t == 0) { ccnt[b] = total; cstart[b * (SS + 1) + total] = SS; }
  ext = extIn; int id = base;
#pragma unroll
  for (int e = 0; e < 16; ++e) {
    int cont = (labv[e] == 1) & ext;
    if (!cont) cstart[b * (SS + 1) + id++] = t * 16 + e;
    ext = (labv[e] == 0) | cont;
  }
}

// ---------------- kernel 4: segment-mean pooling (1 wave / chunk) ----------
__global__ __launch_bounds__(256) void k_pool(
    const float* __restrict__ h, const int* __restrict__ cstart,
    const int* __restrict__ ccnt, u16* __restrict__ cemb)
{
  const int t = threadIdx.x, w = t >> 6, lane = t & 63;
  const int gw = blockIdx.x * 4 + w;
  const int b = gw >> 12, c = gw & (SS - 1);
  u16* out = cemb + (size_t)gw * DD + lane * 16;
  if (c >= ccnt[b]) {
    ushort8 z = {0, 0, 0, 0, 0, 0, 0, 0};
    *(ushort8*)out = z; *(ushort8*)(out + 8) = z;
    return;
  }
  const int s0 = cstart[b * (SS + 1) + c], s1 = cstart[b * (SS + 1) + c + 1];
  float acc[16] = {};
  for (int s = s0; s < s1; ++s) {
    const float4* hp = (const float4*)(h + ((size_t)b * SS + s) * DD + lane * 16);
#pragma unroll
    for (int ii = 0; ii < 4; ++ii) {
      float4 v = hp[ii];
      acc[ii * 4 + 0] += v.x; acc[ii * 4 + 1] += v.y;
      acc[ii * 4 + 2] += v.z; acc[ii * 4 + 3] += v.w;
    }
  }
  const float inv = 1.f / (float)(s1 - s0);
  ushort8 o0, o1;
#pragma unroll
  for (int e = 0; e < 8; ++e) { o0[e] = f2bf(acc[e] * inv); o1[e] = f2bf(acc[8 + e] * inv); }
  *(ushort8*)out = o0; *(ushort8*)(out + 8) = o1;
}

// ---------------- 256x256 NT bf16 GEMM, BK=64, 8 waves ----------------------
// TWO phases per K-tile (r5 skeleton per phase: reads; stage; fence; barrier;
// setprio; MFMA [compiler-scheduled lgkm waits]; setprio; gate?; schedbar;
// barrier). P0: read ALL B (8) + A-mh0 (8), 32 MFMA. P1: read A-mh1 (8),
// 32 MFMA. 4 barriers/K-tile (was 8 in r5, 35% MfmaUtil / 535 us).
// LDS region <-> read-phase map: A groups{0,2}=mh0@P0, {1,3}=mh1@P1, B all@P0.
// Staggered stages:  P0(j): Ah1(j+1)->buf^1   [region last read P1(j-1)]
//                    P1(j): Ah0(j+2)+B(j+2)->buf [regions last read P0(j)]
// Gate after P1 MFMA: vmcnt(6) = outstanding{P1(j-1):6, P0(j):2, P1(j):6}=14
// minus 8 oldest -> tile j+1 fully landed. j==NT-2: vmcnt(0). j==NT-1: none.
template <int OUTF32>
__global__ __launch_bounds__(512, 2) void gemm256(
    const u16* __restrict__ A0p, const u16* __restrict__ A1p,
    const u16* __restrict__ A2p, const u16* __restrict__ A3p,
    const u16* __restrict__ Bt, long strideB,
    void* __restrict__ C0, void* __restrict__ C1,
    void* __restrict__ C2, void* __restrict__ C3,
    const float* __restrict__ bias, float scale, int M, int N, int K)
{
  __shared__ u16 lds[65536];  // 128 KB: A dbuf | B dbuf; C-tile overlay after
  u16* ldsA = lds;
  u16* ldsB = lds + 32768;
  const int t = threadIdx.x, lane = t & 63, w = t >> 6;
  const int wr = w >> 2, wc = w & 3;
  const int z = blockIdx.z;
  const u16* A = (z == 0) ? A0p : (z == 1) ? A1p : (z == 2) ? A2p : A3p;
  void* Cp    = (z == 0) ? C0 : (z == 1) ? C1 : (z == 2) ? C2 : C3;
  const u16* B = Bt + (size_t)z * strideB;
  const int bid = blockIdx.y * gridDim.x + blockIdx.x;
  const int swz = xcd_swz(bid, gridDim.x * gridDim.y);
  const int m0 = (swz / gridDim.x) * 256, n0 = (swz % gridDim.x) * 256;

  f32x4 acc[8][4];
#pragma unroll
  for (int i = 0; i < 8; ++i)
#pragma unroll
    for (int j = 0; j < 4; ++j) acc[i][j] = (f32x4){0.f, 0.f, 0.f, 0.f};

  const int trow = t >> 3;
  const u16* Ag = A + (size_t)(m0 + trow) * K + ((t & 7) ^ (trow & 7)) * 8;
  const u16* Bg = B + (size_t)(n0 + trow) * K + ((t & 7) ^ (trow & 7)) * 8;
  u16* dA = ldsA + t * 8;
  u16* dB = ldsB + t * 8;

  // A half0 = row-groups {0,2} (read by mh0), half1 = {1,3} (read by mh1)
#define STG_AH0(BUF, KT) { gload16(Ag + (size_t)(KT),            dA + (BUF) * 16384 + 0 * 4096); \
                           gload16(Ag + (size_t)128 * K + (KT),  dA + (BUF) * 16384 + 2 * 4096); }
#define STG_AH1(BUF, KT) { gload16(Ag + (size_t)64 * K + (KT),   dA + (BUF) * 16384 + 1 * 4096); \
                           gload16(Ag + (size_t)192 * K + (KT),  dA + (BUF) * 16384 + 3 * 4096); }
#define STG_B(BUF, KT)   { gload16(Bg + (size_t)(KT),            dB + (BUF) * 16384 + 0 * 4096); \
                           gload16(Bg + (size_t)64 * K + (KT),   dB + (BUF) * 16384 + 1 * 4096); \
                           gload16(Bg + (size_t)128 * K + (KT),  dB + (BUF) * 16384 + 2 * 4096); \
                           gload16(Bg + (size_t)192 * K + (KT),  dB + (BUF) * 16384 + 3 * 4096); }
#define RD_A(BASE, ROFF) \
  { _Pragma("unroll") for (int mi = 0; mi < 4; ++mi) { \
      af[mi][0] = *(const short8*)((BASE) + (wr * 128 + (ROFF) + mi * 16 + lrow) * 64 + co0); \
      af[mi][1] = *(const short8*)((BASE) + (wr * 128 + (ROFF) + mi * 16 + lrow) * 64 + co1); } }
#define RD_B(BASE) \
  { _Pragma("unroll") for (int ni = 0; ni < 4; ++ni) { \
      bf[ni][0] = *(const short8*)((BASE) + (wc * 64 + ni * 16 + lrow) * 64 + co0); \
      bf[ni][1] = *(const short8*)((BASE) + (wc * 64 + ni * 16 + lrow) * 64 + co1); } }
#define MFMA32(MH) \
  { _Pragma("unroll") for (int ks = 0; ks < 2; ++ks) \
    _Pragma("unroll") for (int mi = 0; mi < 4; ++mi) \
      _Pragma("unroll") for (int ni = 0; ni < 4; ++ni) \
        acc[(MH) * 4 + mi][ni] = __builtin_amdgcn_mfma_f32_16x16x32_bf16( \
            af[mi][ks], bf[ni][ks], acc[(MH) * 4 + mi][ni], 0, 0, 0); }

  const int lrow = lane & 15, hi = lane >> 4;
  const int co0 = (hi ^ (lrow & 7)) * 8;
  const int co1 = ((4 + hi) ^ (lrow & 7)) * 8;

  const int NT = K >> 6;
  // prologue: tile0 full (8), tile1 Ah0+B (6); Ah1(tile1) staged at iter0-P0.
  STG_AH0(0, 0); STG_AH1(0, 0); STG_B(0, 0);
  if (NT > 1) {
    STG_AH0(1, 64); STG_B(1, 64);
    asm volatile("s_waitcnt vmcnt(6)" ::: "memory");  // 14 outstanding -> tile0 done
  } else {
    asm volatile("s_waitcnt vmcnt(0)" ::: "memory");
  }
  __builtin_amdgcn_s_barrier();
  CFENCE;

  short8 af[4][2], bf[4][2];
  for (int j = 0; j < NT; ++j) {
    const int cur = j & 1;
    const u16* bufA = ldsA + cur * 16384;
    const u16* bufB = ldsB + cur * 16384;
    // ---- P0: read B(all) + A-mh0; stage Ah1(j+1)->buf^1; MFMA mh0
    RD_A(bufA, 0);
    RD_B(bufB);
    if (j + 1 < NT) STG_AH1(cur ^ 1, (j + 1) << 6);
    CFENCE;
    __builtin_amdgcn_s_barrier();
    __builtin_amdgcn_s_setprio(1);
    MFMA32(0);
    __builtin_amdgcn_s_setprio(0);
    __builtin_amdgcn_sched_barrier(0);
    __builtin_amdgcn_s_barrier();
    CFENCE;
    // ---- P1: read A-mh1; stage Ah0(j+2)+B(j+2)->buf; MFMA mh1; vmcnt gate
    RD_A(bufA, 64);
    if (j + 2 < NT) { STG_AH0(cur, (j + 2) << 6); STG_B(cur, (j + 2) << 6); }
    CFENCE;
    __builtin_amdgcn_s_barrier();
    __builtin_amdgcn_s_setprio(1);
    MFMA32(1);
    __builtin_amdgcn_s_setprio(0);
    if (j + 2 < NT)       asm volatile("s_waitcnt vmcnt(6)" ::: "memory");
    else if (j + 2 == NT) asm volatile("s_waitcnt vmcnt(0)" ::: "memory");
    __builtin_amdgcn_sched_barrier(0);
    __builtin_amdgcn_s_barrier();
    CFENCE;
  }

  // epilogue. frag (m,n): row_local = wr*128 + m*16 + (lane>>4)*4 + q,
  // col_local = wc*64 + n*16 + (lane&15)
  if (OUTF32) {
    const int rowb = m0 + wr * 128 + (lane >> 4) * 4;
#pragma unroll
    for (int n = 0; n < 4; ++n) {
      const int col = n0 + wc * 64 + n * 16 + (lane & 15);
      const float bv = bias ? bias[col] : 0.f;
#pragma unroll
      for (int m = 0; m < 8; ++m)
#pragma unroll
        for (int q = 0; q < 4; ++q)
          ((float*)Cp)[(size_t)(rowb + m * 16 + q) * N + col] = acc[m][n][q] * scale + bv;
    }
  } else {
    // stage C tile in LDS (reuse staging buffers), then coalesced copy-out
    __syncthreads();
    u16* cls = lds;
    const int rowl = wr * 128 + (lane >> 4) * 4;
#pragma unroll
    for (int n = 0; n < 4; ++n) {
      const int coll = wc * 64 + n * 16 + (lane & 15);
      const float bv = bias ? bias[n0 + coll] : 0.f;
#pragma unroll
      for (int m = 0; m < 8; ++m)
#pragma unroll
        for (int q = 0; q < 4; ++q)
          cls[(rowl + m * 16 + q) * 256 + coll] = f2bf(acc[m][n][q] * scale + bv);
    }
    __syncthreads();
    u16* Cu = (u16*)Cp;
#pragma unroll
    for (int ps = 0; ps < 16; ++ps) {
      const int f = ps * 512 + t;
      const int row = f >> 5, col8 = (f & 31) * 8;
      *(ushort8*)(Cu + (size_t)(m0 + row) * N + n0 + col8) =
          *(const ushort8*)(cls + row * 256 + col8);
    }
  }
#undef STG_AH0
#undef STG_AH1
#undef STG_B
#undef RD_A
#undef RD_B
#undef MFMA32
}

// ---------------- masked row softmax, bf16 in-place, z-folded ---------------
__global__ __launch_bounds__(256) void k_softmax(
    u16* __restrict__ s0, u16* __restrict__ s1,
    u16* __restrict__ s2, u16* __restrict__ s3, const int* __restrict__ ccnt)
{
  const int t = threadIdx.x, lane = t & 63, w = t >> 6;
  const int row = blockIdx.x, b = blockIdx.y;
  u16* sc = (b == 0) ? s0 : (b == 1) ? s1 : (b == 2) ? s2 : s3;
  const int Cb = ccnt[b];
  u16* p = sc + (size_t)row * SS + t * 16;
  ushort8 v0 = *(ushort8*)p, v1 = *(ushort8*)(p + 8);
  float x[16];
#pragma unroll
  for (int e = 0; e < 8; ++e) { x[e] = bf2f(v0[e]); x[8 + e] = bf2f(v1[e]); }
  const int cb0 = t * 16;
  float m = -1e30f;
#pragma unroll
  for (int e = 0; e < 16; ++e) if (cb0 + e < Cb) m = fmaxf(m, x[e]);
#pragma unroll
  for (int off = 32; off; off >>= 1) m = fmaxf(m, __shfl_xor(m, off));
  __shared__ float red[4], red2[4];
  if (lane == 0) red[w] = m;
  __syncthreads();
  m = fmaxf(fmaxf(red[0], red[1]), fmaxf(red[2], red[3]));
  float ssum = 0.f;
#pragma unroll
  for (int e = 0; e < 16; ++e) {
    float ev = (cb0 + e < Cb) ? __expf(x[e] - m) : 0.f;
    x[e] = ev; ssum += ev;
  }
#pragma unroll
  for (int off = 32; off; off >>= 1) ssum += __shfl_xor(ssum, off);
  if (lane == 0) red2[w] = ssum;
  __syncthreads();
  ssum = red2[0] + red2[1] + red2[2] + red2[3];
  const float inv = 1.f / ssum;
#pragma unroll
  for (int e = 0; e < 8; ++e) { v0[e] = f2bf(x[e] * inv); v1[e] = f2bf(x[8 + e] * inv); }
  *(ushort8*)p = v0; *(ushort8*)(p + 8) = v1;
}

// ---------------- bf16 transpose v[b][c][d] -> vT[b][d][c] ------------------
__global__ __launch_bounds__(256) void k_transpose(
    const u16* __restrict__ v, u16* __restrict__ vt)
{
  __shared__ u16 ts[64][80];
  const int t = threadIdx.x;
  const int d0 = blockIdx.x * 64, c0 = blockIdx.y * 64, b = blockIdx.z;
#pragma unroll
  for (int p = 0; p < 2; ++p) {
    const int idx = p * 256 + t, r = idx >> 3, cc = idx & 7;
    ushort8 val = *(const ushort8*)(v + ((size_t)b * SS + c0 + r) * DD + d0 + cc * 8);
    *(ushort8*)&ts[r][cc * 8] = val;
  }
  __syncthreads();
#pragma unroll
  for (int p = 0; p < 2; ++p) {
    const int idx = p * 256 + t, r = idx >> 3, cc = idx & 7;
    ushort8 o;
#pragma unroll
    for (int e = 0; e < 8; ++e) o[e] = ts[cc * 8 + e][r];
    *(ushort8*)(vt + ((size_t)b * DD + d0 + r) * SS + c0 + cc * 8) = o;
  }
}

// ---------------- loss finalize ---------------------------------------------
__global__ __launch_bounds__(256) void k_lossfin(
    const float* __restrict__ part, float* __restrict__ out)
{
  const int t = threadIdx.x, lane = t & 63, w = t >> 6;
  float s = 0.f;
  for (int i = t; i < 4096; i += 256) s += part[i];
#pragma unroll
  for (int off = 32; off; off >>= 1) s += __shfl_xor(s, off);
  __shared__ float r[4];
  if (lane == 0) r[w] = s;
  __syncthreads();
  if (t == 0) out[0] = (r[0] + r[1] + r[2] + r[3]) * (1.f / (NB * SS));
}

extern "C" void kernel_launch(void* const* d_in, const int* in_sizes, int n_in,
                              void* d_out, int out_size, void* d_ws, size_t ws_size,
                              hipStream_t stream) {
  const float* h  = (const float*)d_in[0];
  const int* plab = (const int*)d_in[1];
  const float* Wl = (const float*)d_in[2];
  const float* bl = (const float*)d_in[3];
  const float* Wq = (const float*)d_in[4];
  const float* bq = (const float*)d_in[5];
  const float* Wk = (const float*)d_in[6];
  const float* bk = (const float*)d_in[7];
  const float* Wv = (const float*)d_in[8];
  const float* bv = (const float*)d_in[9];
  const float* Wo = (const float*)d_in[10];
  const float* bo = (const float*)d_in[11];
  float* out = (float*)d_out;

  char* ws = (char*)d_ws;
  const size_t SZ = (size_t)NB * SS * DD * 2;  // 32 MB
  const size_t SD = (size_t)SS * DD;           // per-batch elems
  u16* h16      = (u16*)(ws + 0 * SZ);  // dead after q GEMM -> scores[2]
  u16* cemb     = (u16*)(ws + 1 * SZ);  // dead after k,v GEMM -> scores[3]
  u16* q        = (u16*)(ws + 2 * SZ);
  u16* kk       = (u16*)(ws + 3 * SZ);
  u16* vv       = (u16*)(ws + 4 * SZ);  // dead after transpose -> attended
  u16* vt       = (u16*)(ws + 5 * SZ);
  u16* Wt       = (u16*)(ws + 6 * SZ);  // 8 MB
  char* ws2     = ws + 6 * SZ + (size_t)4 * 1024 * 1024 * 2;
  int* pred     = (int*)ws2;
  int* cstart   = (int*)(ws2 + 65536);
  int* ccnt     = (int*)(ws2 + 65536 + 4 * (SS + 1) * 4);
  float* lossPart = (float*)(ws2 + 65536 + 4 * (SS + 1) * 4 + 64);
  u16* s0 = (u16*)d_out;                       // scores borrow d_out + dead bufs
  u16* s1 = (u16*)d_out + (size_t)SS * SS;
  u16* s2 = h16;
  u16* s3 = cemb;
  u16* att = vv;

  k_logits<<<dim3(NB * SS / 4), 256, 0, stream>>>(h, plab, Wl, bl, h16, pred, lossPart);
  k_wconv<<<dim3(4 * 1024 * 1024 / 256), 256, 0, stream>>>(Wq, Wk, Wv, Wo, Wt);
  k_scan<<<dim3(NB), 256, 0, stream>>>(pred, cstart, ccnt);
  k_pool<<<dim3(NB * SS / 4), 256, 0, stream>>>(h, cstart, ccnt, cemb);

  gemm256<0><<<dim3(DD / 256, NB * SS / 256, 1), 512, 0, stream>>>(
      h16, h16, h16, h16, Wt, 0, q, q, q, q, bq, 1.f, NB * SS, DD, DD);
  gemm256<0><<<dim3(DD / 256, NB * SS / 256, 1), 512, 0, stream>>>(
      cemb, cemb, cemb, cemb, Wt + (1 << 20), 0, kk, kk, kk, kk, bk, 1.f, NB * SS, DD, DD);
  gemm256<0><<<dim3(DD / 256, NB * SS / 256, 1), 512, 0, stream>>>(
      cemb, cemb, cemb, cemb, Wt + 2 * (1 << 20), 0, vv, vv, vv, vv, bv, 1.f, NB * SS, DD, DD);
  k_transpose<<<dim3(DD / 64, SS / 64, NB), 256, 0, stream>>>(vv, vt);

  const float scl = 1.f / 32.f;  // 1/sqrt(DC)
  gemm256<0><<<dim3(SS / 256, SS / 256, NB), 512, 0, stream>>>(
      q, q + SD, q + 2 * SD, q + 3 * SD, kk, (long)SD,
      s0, s1, s2, s3, nullptr, scl, SS, SS, DD);
  k_softmax<<<dim3(SS, NB), 256, 0, stream>>>(s0, s1, s2, s3, ccnt);
  gemm256<0><<<dim3(DD / 256, SS / 256, NB), 512, 0, stream>>>(
      s0, s1, s2, s3, vt, (long)SD,
      att, att + SD, att + 2 * SD, att + 3 * SD, nullptr, 1.f, SS, DD, SS);
  gemm256<1><<<dim3(DD / 256, NB * SS / 256, 1), 512, 0, stream>>>(
      att, att, att, att, Wt + 3 * (1 << 20), 0, out, out, out, out, bo, 1.f, NB * SS, DD, DD);
  k_lossfin<<<dim3(1), 256, 0, stream>>>(lossPart, out + (size_t)NB * SS * DD);
}